// Round 6
// baseline (2941.798 us; speedup 1.0000x reference)
//
#include <hip/hip_runtime.h>

#define SS 2048
#define HH 64
#define OO 2

__device__ __forceinline__ float readlane_f(float v, int l) {
    return __int_as_float(__builtin_amdgcn_readlane(__float_as_int(v), l));
}
__device__ __forceinline__ float fast_tanh(float x) {
    float ax = fabsf(x);
    float e = __expf(-2.0f * ax);
    float r = (1.0f - e) * __builtin_amdgcn_rcpf(1.0f + e);
    return copysignf(r, x);
}
__device__ __forceinline__ float fast_sigmoid(float x) {
    return __builtin_amdgcn_rcpf(1.0f + __expf(-x));
}

// load 4 strided weight-column elements into a named float4
#define LD4(V, P, K)                                                        \
    float4 V = make_float4((P)[(K) * HH + j], (P)[((K) + 1) * HH + j],      \
                           (P)[((K) + 2) * HH + j], (P)[((K) + 3) * HH + j])

// gate/hz matvec MAC: h broadcast from registers via readlane
#define MACH(K, W)                                               \
    {                                                            \
        a0 = fmaf(readlane_f(hreg, kb2 + (K) + 0), W.x, a0);     \
        a1 = fmaf(readlane_f(hreg, kb2 + (K) + 1), W.y, a1);     \
        a2 = fmaf(readlane_f(hreg, kb2 + (K) + 2), W.z, a2);     \
        a3 = fmaf(readlane_f(hreg, kb2 + (K) + 3), W.w, a3);     \
    }

// hh-slice MAC: rows tb..tb+7 of Wh[64:]
#define MACT(K, W)                                               \
    {                                                            \
        t0 = fmaf(readlane_f(hreg, tb + (K) + 0), W.x, t0);      \
        t1 = fmaf(readlane_f(hreg, tb + (K) + 1), W.y, t1);      \
        t2 = fmaf(readlane_f(hreg, tb + (K) + 2), W.z, t2);      \
        t3 = fmaf(readlane_f(hreg, tb + (K) + 3), W.w, t3);      \
    }

#define MACB(K, W)                                               \
    {                                                            \
        b0 = fmaf(readlane_f(u, kbase + (K) + 0), W.x, b0);      \
        b1 = fmaf(readlane_f(u, kbase + (K) + 1), W.y, b1);      \
        b2 = fmaf(readlane_f(u, kbase + (K) + 2), W.z, b2);      \
        b3 = fmaf(readlane_f(u, kbase + (K) + 3), W.w, b3);      \
    }

__global__ __launch_bounds__(512)
__attribute__((amdgpu_waves_per_eu(2, 2)))
void pgjanet_kernel(
    const float* __restrict__ x,     // [B,S,2]
    const float* __restrict__ h0,    // [1,B,H]
    const float* __restrict__ Wa,    // [65,64]
    const float* __restrict__ ba,
    const float* __restrict__ Wp1,
    const float* __restrict__ bp1,
    const float* __restrict__ Wp2,
    const float* __restrict__ bp2,
    const float* __restrict__ Wz,    // [128,64]
    const float* __restrict__ bz,
    const float* __restrict__ Wh,    // [128,64]
    const float* __restrict__ bh,
    const float* __restrict__ Wout,  // [64,2]
    const float* __restrict__ bout,
    float* __restrict__ out)         // [B,S,2]
{
    const int b    = blockIdx.x;
    const int tid  = threadIdx.x;    // 0..511
    const int lane = tid & 63;
    const int wid  = tid >> 6;       // 0..7
    const int j    = lane;
    const int gidx = wid >> 1;       // 0:a 1:p1 2:p2 3:hz
    const int half = wid & 1;        // k-half of the gate matvec
    const int kb2  = half * 32;      // gate k-base
    const int tb   = wid * 8;        // hh k-base

    __shared__ float ampL[SS];                       // 8 KB
    __shared__ float cosL[SS];                       // 8 KB
    __shared__ float sinL[SS];                       // 8 KB
    __shared__ __align__(16) float hbuf[32][HH + 1]; // padded
    __shared__ __align__(16) float gp[4][2][HH];     // raw gate/hz half-partials
    __shared__ __align__(16) float hhp[8][HH];       // h@Wh[64:] 8-row partials
    __shared__ __align__(16) float pB[8][HH];        // phase-B partials (folded)
    __shared__ float WoutL[HH * OO];
    __shared__ float boutL[OO];

    // ---- precompute amp / cos / sin tables (coalesced, once) ----
    {
        const float2* xb = (const float2*)(x + (size_t)b * SS * 2);
        #pragma unroll
        for (int it = 0; it < SS / 512; ++it) {
            int i = tid + it * 512;
            float2 v = xb[i];
            float d = v.x * v.x + v.y * v.y;
            float r = sqrtf(d);
            float inv = (d > 0.f) ? __builtin_amdgcn_rcpf(r) : 0.f;
            ampL[i] = r;
            cosL[i] = (d > 0.f) ? v.x * inv : 1.0f;
            sinL[i] = v.y * inv;
        }
    }
    if (tid < HH * OO) WoutL[tid] = Wout[tid];
    if (tid < OO) boutL[tid] = bout[tid];

    // h is register-resident in EVERY wave: lane j holds h[j]
    float hreg = h0[b * HH + lane];

    // ---- phase-A weights: 32-k half of one matvec (8 float4) ----
    const float* Grow;
    const float* scalP = ampL;
    float wrow0 = 0.f, bA = 0.f;
    if (gidx == 0) {
        Grow = Wa + (1 + half * 32) * HH; scalP = ampL;
        if (half == 0) { wrow0 = Wa[j]; bA = ba[j]; }
    } else if (gidx == 1) {
        Grow = Wp1 + (1 + half * 32) * HH; scalP = cosL;
        if (half == 0) { wrow0 = Wp1[j]; bA = bp1[j]; }
    } else if (gidx == 2) {
        Grow = Wp2 + (1 + half * 32) * HH; scalP = sinL;
        if (half == 0) { wrow0 = Wp2[j]; bA = bp2[j]; }
    } else {
        Grow = Wz + (64 + half * 32) * HH;   // hz: h @ Wz[64:]
    }
    LD4(wv0, Grow, 0);  LD4(wv1, Grow, 4);  LD4(wv2, Grow, 8);  LD4(wv3, Grow, 12);
    LD4(wv4, Grow, 16); LD4(wv5, Grow, 20); LD4(wv6, Grow, 24); LD4(wv7, Grow, 28);

    // ---- hh slice: rows [64+8*wid, 64+8*wid+8) of Wh (2 float4) ----
    const float* Trow = Wh + (64 + wid * 8) * HH;
    LD4(wt0, Trow, 0); LD4(wt1, Trow, 4);

    // ---- phase-B weights: 16-k slice of u@Wz (w0-3) / u@Wh (w4-7) ----
    const float* Brow = (wid < 4 ? Wz : Wh) + ((wid & 3) * 16) * HH;
    LD4(wb0, Brow, 0); LD4(wb1, Brow, 4); LD4(wb2, Brow, 8); LD4(wb3, Brow, 12);
    const int kbase = (wid & 3) * 16;

    const float bzr = bz[j];
    const float bhr = bh[j];

    __syncthreads();

    for (int t = 0; t < SS; ++t) {
        const float scal = scalP[t];

        // ---- PHASE A: 32 readlane-MACs (gate/hz) + 8 readlane-MACs (hh) ----
        float a0 = 0.f, a1 = 0.f, a2 = 0.f, a3 = 0.f;
        MACH(0, wv0)  MACH(4, wv1)  MACH(8, wv2)  MACH(12, wv3)
        MACH(16, wv4) MACH(20, wv5) MACH(24, wv6) MACH(28, wv7)
        gp[gidx][half][j] = (a0 + a1) + (a2 + a3) + fmaf(scal, wrow0, bA);

        float t0 = 0.f, t1 = 0.f, t2 = 0.f, t3 = 0.f;
        MACT(0, wt0) MACT(4, wt1)
        const float hh_own = (t0 + t1) + (t2 + t3);
        hhp[wid][j] = hh_own;
        __syncthreads();  // bar1: gp + hhp visible

        // ---- PHASE B: u (redundant) + 16 readlane-MACs + fold ----
        float accB;
        {
            const float av  = fast_tanh(gp[0][0][j] + gp[0][1][j]);
            const float p1v = fast_tanh(gp[1][0][j] + gp[1][1][j]);
            const float p2v = fast_tanh(gp[2][0][j] + gp[2][1][j]);
            float u = av * p1v * p2v * (1.f - av) * (1.f - p1v) * (1.f - p2v);

            float b0 = 0.f, b1 = 0.f, b2 = 0.f, b3 = 0.f;
            MACB(0, wb0) MACB(4, wb1) MACB(8, wb2) MACB(12, wb3)
            accB = (b0 + b1) + (b2 + b3);
            // fold: w0/w1 add the hz halves; w4-7 add own + mate hh partials
            if (wid < 2)       accB += gp[3][wid][j];
            else if (wid >= 4) accB += hh_own + hhp[wid - 4][j];
            pB[wid][j] = accB;
        }
        __syncthreads();  // bar2: pB visible

        // ---- COMBINE (all waves redundantly; h stays in registers) ----
        {
            float zpre = ((pB[0][j] + pB[1][j]) + (pB[2][j] + pB[3][j])) + bzr;
            float z = fast_sigmoid(zpre);
            float hpre = ((pB[4][j] + pB[5][j]) + (pB[6][j] + pB[7][j])) + bhr;
            float hc = fast_tanh(hpre);
            hreg = fmaf(z, hreg - hc, hc);
            if (wid == 7) hbuf[t & 31][j] = hreg;  // wave 7: same-wave order
        }
        // NO bar3: next phase A uses only registers; all LDS hazards are
        // separated by bar1/bar2 of step t+1 (gp: B(t) reads < bar2(t) <
        // A(t+1) writes; pB: C(t) reads < bar1(t+1) < B(t+1) writes;
        // hbuf row r: written at step with (step&31)==r, read by flush(t)
        // with >=2 barriers in between, row 31 same-wave in-order).

        // ---- output flush every 32 steps: [32,64]@[64,2] over 512 lanes ----
        if ((t & 31) == 31) {
            const int tt = tid >> 4;          // 0..31 (tt==31 -> wave 7)
            const int s  = tid & 15;
            const int o  = s & 1;             // 0..1
            const int kq = s >> 1;            // 0..7
            const int kb = kq * 8;
            float acc = 0.f;
            #pragma unroll
            for (int k = 0; k < 8; ++k)
                acc += hbuf[tt][kb + k] * WoutL[(kb + k) * OO + o];
            acc += __shfl_xor(acc, 2);
            acc += __shfl_xor(acc, 4);
            acc += __shfl_xor(acc, 8);
            if (kq == 0)
                out[((size_t)b * SS + (t - 31 + tt)) * OO + o] = acc + boutL[o];
        }
    }
}

extern "C" void kernel_launch(void* const* d_in, const int* in_sizes, int n_in,
                              void* d_out, int out_size, void* d_ws, size_t ws_size,
                              hipStream_t stream) {
    const float* x    = (const float*)d_in[0];
    const float* h0   = (const float*)d_in[1];
    const float* Wa   = (const float*)d_in[2];
    const float* ba   = (const float*)d_in[3];
    const float* Wp1  = (const float*)d_in[4];
    const float* bp1  = (const float*)d_in[5];
    const float* Wp2  = (const float*)d_in[6];
    const float* bp2  = (const float*)d_in[7];
    const float* Wz   = (const float*)d_in[8];
    const float* bz   = (const float*)d_in[9];
    const float* Wh   = (const float*)d_in[10];
    const float* bh   = (const float*)d_in[11];
    const float* Wout = (const float*)d_in[12];
    const float* bout = (const float*)d_in[13];
    float* out = (float*)d_out;

    pgjanet_kernel<<<256, 512, 0, stream>>>(x, h0, Wa, ba, Wp1, bp1, Wp2, bp2,
                                            Wz, bz, Wh, bh, Wout, bout, out);
}

// Round 7
// 2725.274 us; speedup vs baseline: 1.0795x; 1.0795x over previous
//
#include <hip/hip_runtime.h>

#define SS 2048
#define HH 64
#define OO 2
#define NG 14   // float4 weight groups per wave

// ---- dynamic LDS map (float offsets) ----
#define OFF_W    0                            // [8][NG][64] float4
#define W_FLOATS (8 * NG * 64 * 4)            // 28672
#define OFF_XS   (OFF_W + W_FLOATS)           // [SS][2]
#define OFF_HBUF (OFF_XS + SS * 2)            // [32][HH+1]
#define OFF_HL   (OFF_HBUF + 32 * (HH + 1))   // [2][HH]
#define OFF_GP   (OFF_HL + 2 * HH)            // [8][HH]  (gidx*2+half)
#define OFF_HHP  (OFF_GP + 8 * HH)            // [8][HH]
#define OFF_PB   (OFF_HHP + 8 * HH)           // [8][HH]
#define OFF_WOUT (OFF_PB + 8 * HH)            // [HH*OO]
#define OFF_BOUT (OFF_WOUT + HH * OO)         // [OO]
#define LDS_FLOATS (OFF_BOUT + 8)
#define LDS_BYTES  (LDS_FLOATS * 4)

__device__ __forceinline__ float readlane_f(float v, int l) {
    return __int_as_float(__builtin_amdgcn_readlane(__float_as_int(v), l));
}
__device__ __forceinline__ float fast_tanh(float x) {
    float ax = fabsf(x);
    float e = __expf(-2.0f * ax);
    float r = (1.0f - e) * __builtin_amdgcn_rcpf(1.0f + e);
    return copysignf(r, x);
}
__device__ __forceinline__ float fast_sigmoid(float x) {
    return __builtin_amdgcn_rcpf(1.0f + __expf(-x));
}

#define GATHER4(P, K) make_float4((P)[(K) * HH + j], (P)[((K) + 1) * HH + j], \
                                  (P)[((K) + 2) * HH + j], (P)[((K) + 3) * HH + j])

// phase-A MAC: weight group G from LDS (unit-stride b128), h broadcast b128
#define MACWH(G)                            \
    {                                       \
        float4 W = wsl[(G) * 64];           \
        float4 hv = h4h[(G)];               \
        a0 = fmaf(hv.x, W.x, a0);           \
        a1 = fmaf(hv.y, W.y, a1);           \
        a2 = fmaf(hv.z, W.z, a2);           \
        a3 = fmaf(hv.w, W.w, a3);           \
    }

#define MACWT(G, I)                         \
    {                                       \
        float4 W = wsl[(G) * 64];           \
        float4 hv = h4t[(I)];               \
        t0 = fmaf(hv.x, W.x, t0);           \
        t1 = fmaf(hv.y, W.y, t1);           \
        t2 = fmaf(hv.z, W.z, t2);           \
        t3 = fmaf(hv.w, W.w, t3);           \
    }

#define MACB(G, K)                                               \
    {                                                            \
        float4 W = wsl[(G) * 64];                                \
        b0 = fmaf(readlane_f(u, kbase + (K) + 0), W.x, b0);      \
        b1 = fmaf(readlane_f(u, kbase + (K) + 1), W.y, b1);      \
        b2 = fmaf(readlane_f(u, kbase + (K) + 2), W.z, b2);      \
        b3 = fmaf(readlane_f(u, kbase + (K) + 3), W.w, b3);      \
    }

__global__ __launch_bounds__(512)
__attribute__((amdgpu_waves_per_eu(2, 2)))
void pgjanet_kernel(
    const float* __restrict__ x,     // [B,S,2]
    const float* __restrict__ h0,    // [1,B,H]
    const float* __restrict__ Wa,    // [65,64]
    const float* __restrict__ ba,
    const float* __restrict__ Wp1,
    const float* __restrict__ bp1,
    const float* __restrict__ Wp2,
    const float* __restrict__ bp2,
    const float* __restrict__ Wz,    // [128,64]
    const float* __restrict__ bz,
    const float* __restrict__ Wh,    // [128,64]
    const float* __restrict__ bh,
    const float* __restrict__ Wout,  // [64,2]
    const float* __restrict__ bout,
    float* __restrict__ out)         // [B,S,2]
{
    extern __shared__ float lds[];

    const int b    = blockIdx.x;
    const int tid  = threadIdx.x;    // 0..511
    const int lane = tid & 63;
    const int wid  = tid >> 6;       // 0..7
    const int j    = lane;
    const int gidx = wid >> 1;       // 0:a 1:p1 2:p2 3:hz
    const int half = wid & 1;

    float* xs    = lds + OFF_XS;
    float* hbuf  = lds + OFF_HBUF;   // [32][HH+1]
    float* hL    = lds + OFF_HL;     // [2][HH]
    float* gp    = lds + OFF_GP;     // [8][HH]
    float* hhp   = lds + OFF_HHP;    // [8][HH]
    float* pB    = lds + OFF_PB;     // [8][HH]
    float* WoutL = lds + OFF_WOUT;
    float* boutL = lds + OFF_BOUT;

    // ---- stage raw I/Q into LDS (coalesced) ----
    {
        const float2* xb  = (const float2*)(x + (size_t)b * SS * 2);
        float2*       xs2 = (float2*)xs;
        #pragma unroll
        for (int it = 0; it < SS / 512; ++it)
            xs2[tid + it * 512] = xb[tid + it * 512];
    }
    if (tid < HH * OO) WoutL[tid] = Wout[tid];
    if (tid < OO) boutL[tid] = bout[tid];

    float hreg = h0[b * HH + lane];
    if (wid == 0) hL[j] = hreg;      // hL[0]

    // ---- weight sources per wave (same split as R5) ----
    const float* Grow;
    float wrow0 = 0.f, bA = 0.f;
    if (gidx == 0) {
        Grow = Wa + (1 + half * 32) * HH;
        if (half == 0) { wrow0 = Wa[j]; bA = ba[j]; }
    } else if (gidx == 1) {
        Grow = Wp1 + (1 + half * 32) * HH;
        if (half == 0) { wrow0 = Wp1[j]; bA = bp1[j]; }
    } else if (gidx == 2) {
        Grow = Wp2 + (1 + half * 32) * HH;
        if (half == 0) { wrow0 = Wp2[j]; bA = bp2[j]; }
    } else {
        Grow = Wz + (64 + half * 32) * HH;   // hz: h @ Wz[64:]
    }
    const float* Trow = Wh + (64 + wid * 8) * HH;                 // hh slice
    const float* Brow = (wid < 4 ? Wz : Wh) + ((wid & 3) * 16) * HH;  // u@W slice
    const int kbase = (wid & 3) * 16;

    // ---- repack weights into LDS: wave slice [NG][64] float4, unit stride ----
    float4* wsl = (float4*)(lds + OFF_W) + (wid * NG) * 64 + j;
    #pragma unroll
    for (int g = 0; g < 8; ++g) wsl[g * 64] = GATHER4(Grow, g * 4);
    wsl[8 * 64] = GATHER4(Trow, 0);
    wsl[9 * 64] = GATHER4(Trow, 4);
    #pragma unroll
    for (int g = 0; g < 4; ++g) wsl[(10 + g) * 64] = GATHER4(Brow, g * 4);

    const float bzr = bz[j];
    const float bhr = bh[j];

    __syncthreads();

    int cur = 0;
    for (int t = 0; t < SS; ++t) {
        // ---- per-step scalar input (recomputed, no tables) ----
        const float xi = xs[2 * t];
        const float xq = xs[2 * t + 1];
        const float d  = xi * xi + xq * xq;
        const float r  = sqrtf(d);
        const float inv = (d > 0.f) ? __builtin_amdgcn_rcpf(r) : 0.f;
        const float scal = (gidx == 0) ? r
                         : (gidx == 1) ? ((d > 0.f) ? xi * inv : 1.0f)
                                       : xq * inv;

        // ---- PHASE A: 32-MAC half-matvec + 8-MAC hh slice (weights from LDS) ----
        const float4* h4  = (const float4*)(hL + cur * HH);
        const float4* h4h = h4 + half * 8;
        float a0 = 0.f, a1 = 0.f, a2 = 0.f, a3 = 0.f;
        MACWH(0) MACWH(1) MACWH(2) MACWH(3)
        MACWH(4) MACWH(5) MACWH(6) MACWH(7)
        gp[(gidx * 2 + half) * HH + j] =
            (a0 + a1) + (a2 + a3) + fmaf(scal, wrow0, bA);

        const float4* h4t = h4 + wid * 2;   // h[8*wid .. 8*wid+7]
        float t0 = 0.f, t1 = 0.f, t2 = 0.f, t3 = 0.f;
        MACWT(8, 0) MACWT(9, 1)
        const float hh_own = (t0 + t1) + (t2 + t3);
        hhp[wid * HH + j] = hh_own;
        __syncthreads();  // bar1: gp + hhp visible

        // ---- PHASE B: u (redundant) + 16 readlane-MACs + fold ----
        {
            const float av  = fast_tanh(gp[0 * HH + j] + gp[1 * HH + j]);
            const float p1v = fast_tanh(gp[2 * HH + j] + gp[3 * HH + j]);
            const float p2v = fast_tanh(gp[4 * HH + j] + gp[5 * HH + j]);
            float u = av * p1v * p2v * (1.f - av) * (1.f - p1v) * (1.f - p2v);

            float b0 = 0.f, b1 = 0.f, b2 = 0.f, b3 = 0.f;
            MACB(10, 0) MACB(11, 4) MACB(12, 8) MACB(13, 12)
            float accB = (b0 + b1) + (b2 + b3);
            if (wid < 2)       accB += gp[(6 + wid) * HH + j];        // hz halves
            else if (wid >= 4) accB += hh_own + hhp[(wid - 4) * HH + j];
            pB[wid * HH + j] = accB;
        }
        __syncthreads();  // bar2: pB visible

        // ---- COMBINE (all waves redundantly; h in registers) ----
        {
            float zpre = ((pB[0 * HH + j] + pB[1 * HH + j]) +
                          (pB[2 * HH + j] + pB[3 * HH + j])) + bzr;
            float z = fast_sigmoid(zpre);
            float hpre = ((pB[4 * HH + j] + pB[5 * HH + j]) +
                          (pB[6 * HH + j] + pB[7 * HH + j])) + bhr;
            float hc = fast_tanh(hpre);
            hreg = fmaf(z, hreg - hc, hc);
            if (wid == 0) {
                hL[(cur ^ 1) * HH + j] = hreg;
                hbuf[(t & 31) * (HH + 1) + j] = hreg;
            }
        }
        cur ^= 1;
        __syncthreads();  // bar3: h(t+1) + hbuf row visible

        // ---- output flush every 32 steps: [32,64]@[64,2] over 512 lanes ----
        if ((t & 31) == 31) {
            const int tt = tid >> 4;          // 0..31
            const int s  = tid & 15;
            const int o  = s & 1;             // 0..1
            const int kq = s >> 1;            // 0..7
            const int kb = kq * 8;
            float acc = 0.f;
            #pragma unroll
            for (int k = 0; k < 8; ++k)
                acc += hbuf[tt * (HH + 1) + kb + k] * WoutL[(kb + k) * OO + o];
            acc += __shfl_xor(acc, 2);
            acc += __shfl_xor(acc, 4);
            acc += __shfl_xor(acc, 8);
            if (kq == 0)
                out[((size_t)b * SS + (t - 31 + tt)) * OO + o] = acc + boutL[o];
        }
    }
}

extern "C" void kernel_launch(void* const* d_in, const int* in_sizes, int n_in,
                              void* d_out, int out_size, void* d_ws, size_t ws_size,
                              hipStream_t stream) {
    const float* x    = (const float*)d_in[0];
    const float* h0   = (const float*)d_in[1];
    const float* Wa   = (const float*)d_in[2];
    const float* ba   = (const float*)d_in[3];
    const float* Wp1  = (const float*)d_in[4];
    const float* bp1  = (const float*)d_in[5];
    const float* Wp2  = (const float*)d_in[6];
    const float* bp2  = (const float*)d_in[7];
    const float* Wz   = (const float*)d_in[8];
    const float* bz   = (const float*)d_in[9];
    const float* Wh   = (const float*)d_in[10];
    const float* bh   = (const float*)d_in[11];
    const float* Wout = (const float*)d_in[12];
    const float* bout = (const float*)d_in[13];
    float* out = (float*)d_out;

    pgjanet_kernel<<<256, 512, LDS_BYTES, stream>>>(x, h0, Wa, ba, Wp1, bp1,
                                                    Wp2, bp2, Wz, bz, Wh, bh,
                                                    Wout, bout, out);
}

// Round 8
// 1950.013 us; speedup vs baseline: 1.5086x; 1.3976x over previous
//
#include <hip/hip_runtime.h>

#define SS 2048
#define HH 64
#define OO 2

typedef _Float16 h2 __attribute__((ext_vector_type(2)));
typedef _Float16 h8 __attribute__((ext_vector_type(8)));

// ---- dynamic LDS map (byte offsets, all 16B-aligned) ----
#define OFF_W     0                      // [8 waves][7 groups][64 lanes] x 16B
#define W_BYTES   (8 * 7 * 64 * 16)      // 57344
#define OFF_XS    (OFF_W + W_BYTES)      // float2[SS]            16384
#define OFF_HBUF  (OFF_XS + 16384)       // float[32][65]          8320
#define OFF_HLH   (OFF_HBUF + 8320)      // _Float16[8][64]        1024
#define OFF_ULH   (OFF_HLH + 1024)       // _Float16[8][64]        1024
#define OFF_GP    (OFF_ULH + 1024)       // float[8][64]           2048
#define OFF_HHP   (OFF_GP + 2048)        // float[8][64]           2048
#define OFF_PB    (OFF_HHP + 2048)       // float[8][64]           2048
#define OFF_WOUT  (OFF_PB + 2048)        // float[128]              512
#define OFF_BOUT  (OFF_WOUT + 512)       // float[2] + pad
#define LDS_BYTES (OFF_BOUT + 16)

__device__ __forceinline__ float fdot2(h2 a, h2 b, float c) {
#if __has_builtin(__builtin_amdgcn_fdot2)
    return __builtin_amdgcn_fdot2(a, b, c, false);
#else
    return fmaf((float)a[0], (float)b[0], fmaf((float)a[1], (float)b[1], c));
#endif
}
__device__ __forceinline__ void dot8(h8 w, h8 h, float& c0, float& c1,
                                     float& c2, float& c3) {
    h2 w0 = {w[0], w[1]}, w1 = {w[2], w[3]}, w2 = {w[4], w[5]}, w3 = {w[6], w[7]};
    h2 x0 = {h[0], h[1]}, x1 = {h[2], h[3]}, x2 = {h[4], h[5]}, x3 = {h[6], h[7]};
    c0 = fdot2(w0, x0, c0);
    c1 = fdot2(w1, x1, c1);
    c2 = fdot2(w2, x2, c2);
    c3 = fdot2(w3, x3, c3);
}
__device__ __forceinline__ float fast_tanh(float x) {
    float ax = fabsf(x);
    float e = __expf(-2.0f * ax);
    float r = (1.0f - e) * __builtin_amdgcn_rcpf(1.0f + e);
    return copysignf(r, x);
}
__device__ __forceinline__ float fast_sigmoid(float x) {
    return __builtin_amdgcn_rcpf(1.0f + __expf(-x));
}

__global__ __launch_bounds__(512)
__attribute__((amdgpu_waves_per_eu(2, 2)))
void pgjanet_kernel(
    const float* __restrict__ x,     // [B,S,2]
    const float* __restrict__ h0,    // [1,B,H]
    const float* __restrict__ Wa,    // [65,64]
    const float* __restrict__ ba,
    const float* __restrict__ Wp1,
    const float* __restrict__ bp1,
    const float* __restrict__ Wp2,
    const float* __restrict__ bp2,
    const float* __restrict__ Wz,    // [128,64]
    const float* __restrict__ bz,
    const float* __restrict__ Wh,    // [128,64]
    const float* __restrict__ bh,
    const float* __restrict__ Wout,  // [64,2]
    const float* __restrict__ bout,
    float* __restrict__ out)         // [B,S,2]
{
    extern __shared__ __align__(16) char lds[];

    const int b    = blockIdx.x;
    const int tid  = threadIdx.x;    // 0..511
    const int lane = tid & 63;
    const int wid  = tid >> 6;       // 0..7
    const int j    = lane;
    const int gidx = wid >> 1;       // 0:a 1:p1 2:p2 3:hz
    const int half = wid & 1;
    const int kb2  = half * 32;      // gate k-base
    const int tb   = wid * 8;        // hh k-base
    const int kbase = (wid & 3) * 16;

    float*      xsf   = (float*)(lds + OFF_XS);
    float*      hbuf  = (float*)(lds + OFF_HBUF);   // [32][65]
    _Float16*   hLh   = (_Float16*)(lds + OFF_HLH); // [8][64]
    _Float16*   uLh   = (_Float16*)(lds + OFF_ULH); // [8][64]
    float*      gp    = (float*)(lds + OFF_GP);     // [8][64]
    float*      hhp   = (float*)(lds + OFF_HHP);    // [8][64]
    float*      pB    = (float*)(lds + OFF_PB);     // [8][64]
    float*      WoutL = (float*)(lds + OFF_WOUT);
    float*      boutL = (float*)(lds + OFF_BOUT);

    // ---- stage raw I/Q into LDS (coalesced) ----
    {
        const float2* xb  = (const float2*)(x + (size_t)b * SS * 2);
        float2*       xs2 = (float2*)xsf;
        #pragma unroll
        for (int it = 0; it < SS / 512; ++it)
            xs2[tid + it * 512] = xb[tid + it * 512];
    }
    if (tid < HH * OO) WoutL[tid] = Wout[tid];
    if (tid < OO) boutL[tid] = bout[tid];

    // h carried in f32 registers (redundant in every wave); f16 copy per wave
    float hreg = h0[b * HH + lane];
    hLh[wid * 64 + j] = (_Float16)hreg;

    // ---- weight sources per wave (R5 split) ----
    const float* Grow;
    float wrow0 = 0.f, bA = 0.f;
    if (gidx == 0) {
        Grow = Wa + (1 + half * 32) * HH;
        if (half == 0) { wrow0 = Wa[j]; bA = ba[j]; }
    } else if (gidx == 1) {
        Grow = Wp1 + (1 + half * 32) * HH;
        if (half == 0) { wrow0 = Wp1[j]; bA = bp1[j]; }
    } else if (gidx == 2) {
        Grow = Wp2 + (1 + half * 32) * HH;
        if (half == 0) { wrow0 = Wp2[j]; bA = bp2[j]; }
    } else {
        Grow = Wz + (64 + half * 32) * HH;   // hz: h @ Wz[64:]
    }
    const float* Trow = Wh + (64 + wid * 8) * HH;                    // hh slice
    const float* Brow = (wid < 4 ? Wz : Wh) + ((wid & 3) * 16) * HH; // u@W slice

    // ---- repack weights -> LDS f16 pairs: [wid][7 groups][64 lanes] x h8 ----
    {
        h8* wdst = (h8*)(lds + OFF_W) + (wid * 7) * 64 + j;
        #pragma unroll
        for (int g = 0; g < 4; ++g) {           // gate/hz: k = kb2 + 8g .. +7
            h8 v;
            #pragma unroll
            for (int i = 0; i < 8; ++i) v[i] = (_Float16)Grow[(g * 8 + i) * HH + j];
            wdst[g * 64] = v;
        }
        {
            h8 v;                                // hh: rows tb..tb+7 of Wh[64:]
            #pragma unroll
            for (int i = 0; i < 8; ++i) v[i] = (_Float16)Trow[i * HH + j];
            wdst[4 * 64] = v;
        }
        #pragma unroll
        for (int g = 0; g < 2; ++g) {            // B: k = kbase + 8g .. +7
            h8 v;
            #pragma unroll
            for (int i = 0; i < 8; ++i) v[i] = (_Float16)Brow[(g * 8 + i) * HH + j];
            wdst[(5 + g) * 64] = v;
        }
    }

    const float bzr = bz[j];
    const float bhr = bh[j];
    const h8* wsl = (const h8*)(lds + OFF_W) + (wid * 7) * 64 + j;
    const _Float16* hown = hLh + wid * 64;
    _Float16*       uown = uLh + wid * 64;

    __syncthreads();

    for (int t = 0; t < SS; ++t) {
        // ---- per-step scalar input ----
        const float2 xt = ((const float2*)xsf)[t];
        const float d = xt.x * xt.x + xt.y * xt.y;
        float scal;
        if (gidx == 0) {
            scal = sqrtf(d);
        } else {
            const float inv = (d > 0.f) ? __builtin_amdgcn_rcpf(sqrtf(d)) : 0.f;
            scal = (gidx == 1) ? ((d > 0.f) ? xt.x * inv : 1.0f) : xt.y * inv;
        }

        // ---- PHASE A: 32-MAC half-matvec (16 fdot2) + 8-MAC hh (4 fdot2) ----
        float a0 = 0.f, a1 = 0.f, a2 = 0.f, a3 = 0.f;
        #pragma unroll
        for (int g = 0; g < 4; ++g) {
            h8 w  = wsl[g * 64];
            h8 hv = *(const h8*)(hown + kb2 + g * 8);   // broadcast, own copy
            dot8(w, hv, a0, a1, a2, a3);
        }
        gp[(gidx * 2 + half) * 64 + j] =
            (a0 + a1) + (a2 + a3) + fmaf(scal, wrow0, bA);

        float t0 = 0.f, t1 = 0.f, t2 = 0.f, t3 = 0.f;
        {
            h8 w  = wsl[4 * 64];
            h8 hv = *(const h8*)(hown + tb);
            dot8(w, hv, t0, t1, t2, t3);
        }
        const float hh_own = (t0 + t1) + (t2 + t3);
        hhp[wid * 64 + j] = hh_own;
        __syncthreads();  // bar1: gp + hhp visible

        // ---- PHASE B: u (redundant) + 16-MAC slice (8 fdot2) + fold ----
        {
            const float av  = fast_tanh(gp[0 * 64 + j] + gp[1 * 64 + j]);
            const float p1v = fast_tanh(gp[2 * 64 + j] + gp[3 * 64 + j]);
            const float p2v = fast_tanh(gp[4 * 64 + j] + gp[5 * 64 + j]);
            float u = av * p1v * p2v * (1.f - av) * (1.f - p1v) * (1.f - p2v);
            uown[j] = (_Float16)u;   // own-wave copy; in-wave ordering

            float b0 = 0.f, b1 = 0.f, b2 = 0.f, b3 = 0.f;
            #pragma unroll
            for (int g = 0; g < 2; ++g) {
                h8 w  = wsl[(5 + g) * 64];
                h8 uv = *(const h8*)(uown + kbase + g * 8);
                dot8(w, uv, b0, b1, b2, b3);
            }
            float accB = (b0 + b1) + (b2 + b3);
            if (wid < 2)       accB += gp[(6 + wid) * 64 + j];      // hz halves
            else if (wid >= 4) accB += hh_own + hhp[(wid - 4) * 64 + j];
            pB[wid * 64 + j] = accB;
        }
        __syncthreads();  // bar2: pB visible

        // ---- COMBINE (all waves redundantly; h stays f32 in registers) ----
        {
            float zpre = ((pB[0 * 64 + j] + pB[1 * 64 + j]) +
                          (pB[2 * 64 + j] + pB[3 * 64 + j])) + bzr;
            float z = fast_sigmoid(zpre);
            float hpre = ((pB[4 * 64 + j] + pB[5 * 64 + j]) +
                          (pB[6 * 64 + j] + pB[7 * 64 + j])) + bhr;
            float hc = fast_tanh(hpre);
            hreg = fmaf(z, hreg - hc, hc);
            hLh[wid * 64 + j] = (_Float16)hreg;      // own copy for next A
            if (wid == 7) hbuf[(t & 31) * (HH + 1) + j] = hreg;
        }
        // no bar3: next A reads only own-wave LDS; cross-wave hazards are
        // separated by bar1/bar2 of adjacent steps (see analysis).

        // ---- output flush every 32 steps: [32,64]@[64,2] over 512 lanes ----
        if ((t & 31) == 31) {
            const int tt = tid >> 4;          // 0..31 (rows 28-31 -> wave 7)
            const int s  = tid & 15;
            const int o  = s & 1;
            const int kq = s >> 1;            // 0..7
            const int kb = kq * 8;
            float acc = 0.f;
            #pragma unroll
            for (int k = 0; k < 8; ++k)
                acc += hbuf[tt * (HH + 1) + kb + k] * WoutL[(kb + k) * OO + o];
            acc += __shfl_xor(acc, 2);
            acc += __shfl_xor(acc, 4);
            acc += __shfl_xor(acc, 8);
            if (kq == 0)
                out[((size_t)b * SS + (t - 31 + tt)) * OO + o] = acc + boutL[o];
        }
    }
}

extern "C" void kernel_launch(void* const* d_in, const int* in_sizes, int n_in,
                              void* d_out, int out_size, void* d_ws, size_t ws_size,
                              hipStream_t stream) {
    const float* x    = (const float*)d_in[0];
    const float* h0   = (const float*)d_in[1];
    const float* Wa   = (const float*)d_in[2];
    const float* ba   = (const float*)d_in[3];
    const float* Wp1  = (const float*)d_in[4];
    const float* bp1  = (const float*)d_in[5];
    const float* Wp2  = (const float*)d_in[6];
    const float* bp2  = (const float*)d_in[7];
    const float* Wz   = (const float*)d_in[8];
    const float* bz   = (const float*)d_in[9];
    const float* Wh   = (const float*)d_in[10];
    const float* bh   = (const float*)d_in[11];
    const float* Wout = (const float*)d_in[12];
    const float* bout = (const float*)d_in[13];
    float* out = (float*)d_out;

    pgjanet_kernel<<<256, 512, LDS_BYTES, stream>>>(x, h0, Wa, ba, Wp1, bp1,
                                                    Wp2, bp2, Wz, bz, Wh, bh,
                                                    Wout, bout, out);
}

// Round 9
// 1830.289 us; speedup vs baseline: 1.6073x; 1.0654x over previous
//
#include <hip/hip_runtime.h>

#define SS 2048
#define HH 64

typedef _Float16 h2 __attribute__((ext_vector_type(2)));
typedef unsigned int uint;

__device__ __forceinline__ float fdot2f(uint w, uint x, float c) {
#if __has_builtin(__builtin_amdgcn_fdot2)
    return __builtin_amdgcn_fdot2(__builtin_bit_cast(h2, w),
                                  __builtin_bit_cast(h2, x), c, false);
#else
    h2 a = __builtin_bit_cast(h2, w), b = __builtin_bit_cast(h2, x);
    return fmaf((float)a[0], (float)b[0], fmaf((float)a[1], (float)b[1], c));
#endif
}
__device__ __forceinline__ uint pack2(float a, float b) {
    h2 v = {(_Float16)a, (_Float16)b};
    return __builtin_bit_cast(uint, v);
}
__device__ __forceinline__ float fast_tanh(float x) {
    float ax = fabsf(x);
    float e = __expf(-2.0f * ax);
    float r = (1.0f - e) * __builtin_amdgcn_rcpf(1.0f + e);
    return copysignf(r, x);
}
__device__ __forceinline__ float fast_sigmoid(float x) {
    return __builtin_amdgcn_rcpf(1.0f + __expf(-x));
}

__global__ __launch_bounds__(64)
__attribute__((amdgpu_waves_per_eu(1, 1)))
void pgjanet_kernel(
    const float* __restrict__ x,     // [B,S,2]
    const float* __restrict__ h0,    // [1,B,H]
    const float* __restrict__ Wa,    // [65,64]
    const float* __restrict__ ba,
    const float* __restrict__ Wp1,
    const float* __restrict__ bp1,
    const float* __restrict__ Wp2,
    const float* __restrict__ bp2,
    const float* __restrict__ Wz,    // [128,64]
    const float* __restrict__ bz,
    const float* __restrict__ Wh,    // [128,64]
    const float* __restrict__ bh,
    const float* __restrict__ Wout,  // [64,2]
    const float* __restrict__ bout,
    float* __restrict__ out)         // [B,S,2]
{
    const int b = blockIdx.x;
    const int j = threadIdx.x;       // 0..63, one wave per block

    __shared__ float2 xs2[SS];                         // 16 KB
    __shared__ __align__(16) unsigned short hpk[HH];   // h as f16
    __shared__ __align__(16) unsigned short upk[HH];   // u as f16
    __shared__ float hbufL[32 * 65];                   // padded stash
    __shared__ float WoutT[2 * 68];                    // transposed, padded

    // ---- stage x[b] (coalesced), Wout^T ----
    {
        const float2* xb = (const float2*)(x + (size_t)b * SS * 2);
        #pragma unroll
        for (int it = 0; it < SS / 64; ++it)
            xs2[j + it * 64] = xb[j + it * 64];
    }
    WoutT[0 * 68 + j] = Wout[j * 2 + 0];
    WoutT[1 * 68 + j] = Wout[j * 2 + 1];
    const float bo = bout[j & 1];

    // ---- per-lane scalars ----
    const float w0a  = Wa[j],  baR  = ba[j];
    const float w0p1 = Wp1[j], bp1R = bp1[j];
    const float w0p2 = Wp2[j], bp2R = bp2[j];
    const float bzR  = bz[j],  bhR  = bh[j];

    // ---- weights -> packed f16 pairs in registers (224 VGPRs) ----
    uint wA[32], wP1[32], wP2[32], wZh[32], wHh[32], wZu[32], wHu[32];
    #pragma unroll
    for (int k = 0; k < 32; ++k) {
        wA[k]  = pack2(Wa [(1 + 2*k) * HH + j], Wa [(2 + 2*k) * HH + j]);
        wP1[k] = pack2(Wp1[(1 + 2*k) * HH + j], Wp1[(2 + 2*k) * HH + j]);
        wP2[k] = pack2(Wp2[(1 + 2*k) * HH + j], Wp2[(2 + 2*k) * HH + j]);
        wZu[k] = pack2(Wz [(2*k) * HH + j],      Wz [(2*k + 1) * HH + j]);
        wZh[k] = pack2(Wz [(64 + 2*k) * HH + j], Wz [(65 + 2*k) * HH + j]);
        wHu[k] = pack2(Wh [(2*k) * HH + j],      Wh [(2*k + 1) * HH + j]);
        wHh[k] = pack2(Wh [(64 + 2*k) * HH + j], Wh [(65 + 2*k) * HH + j]);
    }
    // pin: opaque values can't be rematerialized/sunk into the loop
    #pragma unroll
    for (int k = 0; k < 32; ++k) {
        asm volatile("" : "+v"(wA[k]), "+v"(wP1[k]), "+v"(wP2[k]), "+v"(wZh[k]));
        asm volatile("" : "+v"(wHh[k]), "+v"(wZu[k]), "+v"(wHu[k]));
    }

    // ---- initial hidden state (f32 in reg, f16 copy in LDS) ----
    float hreg = h0[b * HH + j];
    hpk[j] = __builtin_bit_cast(unsigned short, (_Float16)hreg);

    const uint4* hp4 = (const uint4*)hpk;   // 8 x b128 broadcast reads
    const uint4* up4 = (const uint4*)upk;

    for (int t = 0; t < SS; ++t) {
        // ---- scalar inputs (amp, cos, sin) ----
        const float2 xt = xs2[t];
        const float d = xt.x * xt.x + xt.y * xt.y;
        const float inv = (d > 0.f) ? __builtin_amdgcn_rsqf(d) : 0.f;
        const float amp = d * inv;                    // sqrt(d), 0 at d=0
        const float ca  = (d > 0.f) ? xt.x * inv : 1.0f;
        const float sa  = xt.y * inv;

        // ---- h pairs (broadcast; waits on last iter's ds_write) ----
        uint hp[32];
        #pragma unroll
        for (int g = 0; g < 8; ++g) {
            uint4 v = hp4[g];
            hp[4*g+0] = v.x; hp[4*g+1] = v.y; hp[4*g+2] = v.z; hp[4*g+3] = v.w;
        }

        // ---- 5 h-matvecs, 20 independent acc chains (160 fdot2) ----
        float aA[4]  = {0,0,0,0}, aP1[4] = {0,0,0,0}, aP2[4] = {0,0,0,0};
        float aZh[4] = {0,0,0,0}, aHh[4] = {0,0,0,0};
        #pragma unroll
        for (int g = 0; g < 32; ++g) {
            const uint hpg = hp[g];
            aA [g & 3] = fdot2f(wA [g], hpg, aA [g & 3]);
            aP1[g & 3] = fdot2f(wP1[g], hpg, aP1[g & 3]);
            aP2[g & 3] = fdot2f(wP2[g], hpg, aP2[g & 3]);
            aZh[g & 3] = fdot2f(wZh[g], hpg, aZh[g & 3]);
            aHh[g & 3] = fdot2f(wHh[g], hpg, aHh[g & 3]);
        }
        const float a_  = fast_tanh(((aA [0]+aA [1])+(aA [2]+aA [3])) + fmaf(amp, w0a,  baR));
        const float p1_ = fast_tanh(((aP1[0]+aP1[1])+(aP1[2]+aP1[3])) + fmaf(ca,  w0p1, bp1R));
        const float p2_ = fast_tanh(((aP2[0]+aP2[1])+(aP2[2]+aP2[3])) + fmaf(sa,  w0p2, bp2R));
        const float zh  = (aZh[0]+aZh[1]) + (aZh[2]+aZh[3]);
        const float hh  = (aHh[0]+aHh[1]) + (aHh[2]+aHh[3]);

        const float u = a_ * p1_ * p2_ * (1.f - a_) * (1.f - p1_) * (1.f - p2_);
        upk[j] = __builtin_bit_cast(unsigned short, (_Float16)u);

        // ---- u pairs (broadcast, same wave -> lgkmcnt only) ----
        uint up[32];
        #pragma unroll
        for (int g = 0; g < 8; ++g) {
            uint4 v = up4[g];
            up[4*g+0] = v.x; up[4*g+1] = v.y; up[4*g+2] = v.z; up[4*g+3] = v.w;
        }

        // ---- 2 u-matvecs (64 fdot2) ----
        float zU[4] = {0,0,0,0}, hU[4] = {0,0,0,0};
        #pragma unroll
        for (int g = 0; g < 32; ++g) {
            const uint upg = up[g];
            zU[g & 3] = fdot2f(wZu[g], upg, zU[g & 3]);
            hU[g & 3] = fdot2f(wHu[g], upg, hU[g & 3]);
        }
        const float z  = fast_sigmoid(((zU[0]+zU[1]) + (zU[2]+zU[3])) + zh + bzR);
        const float hc = fast_tanh  (((hU[0]+hU[1]) + (hU[2]+hU[3])) + hh + bhR);
        hreg = fmaf(z, hreg - hc, hc);

        hpk[j] = __builtin_bit_cast(unsigned short, (_Float16)hreg);
        hbufL[(t & 31) * 65 + j] = hreg;

        // ---- output flush every 32 steps (within-wave, in-order) ----
        if ((t & 31) == 31) {
            const int r = j >> 1;      // row 0..31
            const int o = j & 1;       // output 0..1
            float acc = 0.f;
            #pragma unroll
            for (int k = 0; k < 64; ++k)
                acc += hbufL[r * 65 + k] * WoutT[o * 68 + k];
            out[((size_t)b * SS + (t - 31 + r)) * 2 + o] = acc + bo;
        }
    }
}

extern "C" void kernel_launch(void* const* d_in, const int* in_sizes, int n_in,
                              void* d_out, int out_size, void* d_ws, size_t ws_size,
                              hipStream_t stream) {
    const float* x    = (const float*)d_in[0];
    const float* h0   = (const float*)d_in[1];
    const float* Wa   = (const float*)d_in[2];
    const float* ba   = (const float*)d_in[3];
    const float* Wp1  = (const float*)d_in[4];
    const float* bp1  = (const float*)d_in[5];
    const float* Wp2  = (const float*)d_in[6];
    const float* bp2  = (const float*)d_in[7];
    const float* Wz   = (const float*)d_in[8];
    const float* bz   = (const float*)d_in[9];
    const float* Wh   = (const float*)d_in[10];
    const float* bh   = (const float*)d_in[11];
    const float* Wout = (const float*)d_in[12];
    const float* bout = (const float*)d_in[13];
    float* out = (float*)d_out;

    pgjanet_kernel<<<256, 64, 0, stream>>>(x, h0, Wa, ba, Wp1, bp1, Wp2, bp2,
                                           Wz, bz, Wh, bh, Wout, bout, out);
}